// Round 6
// baseline (148.796 us; speedup 1.0000x reference)
//
#include <hip/hip_runtime.h>
#include <hip/hip_bf16.h>
#include <hip/hip_cooperative_groups.h>

namespace cg = cooperative_groups;

#define EPSV 1e-5f

typedef __attribute__((ext_vector_type(8))) short short8v;
typedef __attribute__((ext_vector_type(4))) float float4v;

__device__ inline unsigned short f2bf(float x) {
  __hip_bfloat16 h = __float2bfloat16(x);   // RNE
  return *reinterpret_cast<unsigned short*>(&h);
}

// ------------- Kernel 1: pool (+softmax scale) with quant tail blocks -------
// Blocks [0, 28672): one (b, global-channel) row of adaptive avg-pool -> bf16.
// Blocks [28672, 28800): 2-bit weight quant row -> exact bf16 q + f32 scale.
__global__ __launch_bounds__(256) void pool_quant_kernel(
    const float* __restrict__ s1, const float* __restrict__ s2,
    const float* __restrict__ s3, const float* __restrict__ alpha,
    const float* __restrict__ w, unsigned short* __restrict__ fusedb,
    unsigned short* __restrict__ qbf, float* __restrict__ scales) {
  __shared__ float row[5000];
  int bid = blockIdx.x;
  int t = threadIdx.x;

  if (bid >= 28672) {               // ---- quant tail ----
    int o = bid - 28672;            // 0..127
    const float* wr = w + o * 448;
    float m = 0.f;
    for (int c = t; c < 448; c += 256) m = fmaxf(m, fabsf(wr[c]));
    float* sm = row;                // reuse LDS
    for (int off = 32; off; off >>= 1) m = fmaxf(m, __shfl_down(m, off, 64));
    if ((t & 63) == 0) sm[t >> 6] = m;
    __syncthreads();
    m = fmaxf(fmaxf(sm[0], sm[1]), fmaxf(sm[2], sm[3]));
    float scale = fmaxf(m, 1e-8f);  // qp = 1 for 2-bit symmetric
    for (int c = t; c < 448; c += 256) {
      float q = rintf(wr[c] / scale);      // RNE == jnp.round
      q = fminf(fmaxf(q, -2.f), 1.f);
      qbf[o * 448 + c] = f2bf(q);          // q in {-2,-1,0,1}: exact bf16
    }
    if (t == 0) scales[o] = scale;
    return;
  }

  // ---- pool path ----
  int b = bid / 448;
  int cg_ = bid % 448;
  const float* src; int C, L, c, widx;
  if (cg_ < 256)      { src = s1; C = 256; L = 5000; c = cg_;       widx = 0; }
  else if (cg_ < 384) { src = s2; C = 128; L = 2500; c = cg_ - 256; widx = 1; }
  else                { src = s3; C = 64;  L = 625;  c = cg_ - 384; widx = 2; }

  float a0 = alpha[0], a1 = alpha[1], a2 = alpha[2];
  float mx = fmaxf(a0, fmaxf(a1, a2));
  float e0 = expf(a0 - mx), e1 = expf(a1 - mx), e2 = expf(a2 - mx);
  float wst = ((widx == 0) ? e0 : (widx == 1) ? e1 : e2) / (e0 + e1 + e2);

  const float* rowp = src + ((size_t)b * C + c) * L;
  if ((L & 3) == 0) {
    const float4* rp4 = (const float4*)rowp;
    int L4 = L >> 2;
    for (int i = t; i < L4; i += 256) {
      float4 v = rp4[i];
      int j = i << 2;
      row[j] = v.x; row[j + 1] = v.y; row[j + 2] = v.z; row[j + 3] = v.w;
    }
  } else {
    for (int i = t; i < L; i += 256) row[i] = rowp[i];
  }
  __syncthreads();

  int l = t;
  int start = (l * L) >> 8;
  int end = ((l + 1) * L + 255) >> 8;
  float s = 0.f;
  for (int i = start; i < end; ++i) s += row[i];
  float v = s / (float)(end - start) * wst;
  fusedb[((size_t)b * 448 + cg_) * 256 + l] = f2bf(v);
}

// ------------- Kernel 2 (cooperative): GEMM + BN-stats + ELU + mean --------
// Grid (64 b, 2 o-tiles), 256 thr (4 waves, each wave: 16 rows x 256 cols).
// y never touches global memory: held in regs across one grid sync.
__global__ __launch_bounds__(256) void fused_tail_kernel(
    const unsigned short* __restrict__ qbf, const float* __restrict__ scales,
    const unsigned short* __restrict__ fusedb, const float* __restrict__ bias,
    const float* __restrict__ gamma, const float* __restrict__ beta,
    float* __restrict__ Psum, float* __restrict__ Pssq,
    float* __restrict__ out) {
  __shared__ __align__(16) unsigned short Asm[64][40];  // [row][k]
  __shared__ __align__(16) unsigned Bsm32[16][257];     // [k-pair][n 0..255] packed 2xbf16
  __shared__ float red_s[64][4], red_q[64][4];
  __shared__ float smean[64], srsig[64], sgam[64], sbet[64];

  int b = blockIdx.x;
  int o0 = blockIdx.y * 64;
  int tid = threadIdx.x;
  int wv = tid >> 6, lane = tid & 63;
  int lrow = lane & 15, lg = lane >> 4;
  const unsigned short* Fp = fusedb + (size_t)b * 448 * 256;

  float4v acc[16];
  #pragma unroll
  for (int nf = 0; nf < 16; ++nf) acc[nf] = (float4v){0.f, 0.f, 0.f, 0.f};

  for (int c0 = 0; c0 < 448; c0 += 32) {
    {  // stage A: 64 rows x 32 k
      int r = tid >> 2, k0a = (tid & 3) * 8;
      *(short8v*)&Asm[r][k0a] =
          *(const short8v*)(qbf + (size_t)(o0 + r) * 448 + c0 + k0a);
    }
    // stage B: 32 k x 256 n, packed as k-pairs into u32
    #pragma unroll
    for (int cc = 0; cc < 2; ++cc) {
      int ci = tid + 256 * cc;          // 0..511
      int kp = ci >> 5;                 // 0..15
      int n0 = (ci & 31) * 8;           // 0..248
      const unsigned short* g0 = Fp + (size_t)(c0 + 2 * kp) * 256 + n0;
      short8v v0 = *(const short8v*)g0;
      short8v v1 = *(const short8v*)(g0 + 256);
      #pragma unroll
      for (int j = 0; j < 8; ++j) {
        Bsm32[kp][n0 + j] =
            (((unsigned)(unsigned short)v1[j]) << 16) | (unsigned short)v0[j];
      }
    }
    __syncthreads();

    short8v af = *(const short8v*)&Asm[wv * 16 + lrow][lg * 8];
    #pragma unroll
    for (int nf = 0; nf < 16; ++nf) {
      int n = nf * 16 + lrow;
      int tmp[4];
      tmp[0] = (int)Bsm32[lg * 4 + 0][n];
      tmp[1] = (int)Bsm32[lg * 4 + 1][n];
      tmp[2] = (int)Bsm32[lg * 4 + 2][n];
      tmp[3] = (int)Bsm32[lg * 4 + 3][n];
      short8v bf;
      __builtin_memcpy(&bf, tmp, 16);
      acc[nf] = __builtin_amdgcn_mfma_f32_16x16x32_bf16(af, bf, acc[nf], 0, 0, 0);
    }
    __syncthreads();
  }

  // epilogue A: scale+bias in-place, BN partials per (channel, b)
  #pragma unroll
  for (int reg = 0; reg < 4; ++reg) {
    int r = o0 + wv * 16 + lg * 4 + reg;
    float sc = scales[r], bv = bias[r];
    float sv = 0.f, qv = 0.f;
    #pragma unroll
    for (int nf = 0; nf < 16; ++nf) {
      float v = acc[nf][reg] * sc + bv;
      acc[nf][reg] = v;               // y kept in regs
      sv += v; qv += v * v;
    }
    #pragma unroll
    for (int m = 1; m < 16; m <<= 1) {
      sv += __shfl_xor(sv, m, 64);
      qv += __shfl_xor(qv, m, 64);
    }
    if (lrow == 0) {
      Psum[(size_t)r * 64 + b] = sv;
      Pssq[(size_t)r * 64 + b] = qv;
    }
  }

  __threadfence();
  cg::this_grid().sync();

  // phase B: stats for this block's 64 channels (redundant across b-blocks)
  {
    int ch = tid >> 2, part = tid & 3;
    const float* Pp = Psum + (size_t)(o0 + ch) * 64 + part * 16;
    const float* Qp = Pssq + (size_t)(o0 + ch) * 64 + part * 16;
    float s = 0.f, q = 0.f;
    #pragma unroll
    for (int i = 0; i < 16; ++i) { s += Pp[i]; q += Qp[i]; }
    red_s[ch][part] = s; red_q[ch][part] = q;
    __syncthreads();
    if (tid < 64) {
      float S = red_s[tid][0] + red_s[tid][1] + red_s[tid][2] + red_s[tid][3];
      float Q = red_q[tid][0] + red_q[tid][1] + red_q[tid][2] + red_q[tid][3];
      float mean = S * (1.f / 16384.f);
      float var = Q * (1.f / 16384.f) - mean * mean;
      smean[tid] = mean;
      srsig[tid] = rsqrtf(var + EPSV);
      sgam[tid] = gamma[o0 + tid];
      sbet[tid] = beta[o0 + tid];
    }
    __syncthreads();
  }

  // phase C: BN + ELU + mean over L, direct out write
  #pragma unroll
  for (int reg = 0; reg < 4; ++reg) {
    int chl = wv * 16 + lg * 4 + reg;
    float a = srsig[chl] * sgam[chl];
    float bb = sbet[chl] - smean[chl] * a;
    float es = 0.f;
    #pragma unroll
    for (int nf = 0; nf < 16; ++nf) {
      float yn = acc[nf][reg] * a + bb;
      es += yn > 0.f ? yn : expm1f(yn);
    }
    #pragma unroll
    for (int m = 1; m < 16; m <<= 1) es += __shfl_xor(es, m, 64);
    if (lrow == 0) out[(size_t)b * 128 + o0 + chl] = es * (1.f / 256.f);
  }
}

// ================= fallback chain (R3-proven, non-cooperative) ==============
__global__ __launch_bounds__(256) void mfma_gemm_kernel(
    const unsigned short* __restrict__ qbf, const float* __restrict__ scales,
    const unsigned short* __restrict__ fusedb, const float* __restrict__ bias,
    float* __restrict__ y, float* __restrict__ Psum, float* __restrict__ Pssq) {
  __shared__ __align__(16) unsigned short Asm[64][40];
  __shared__ __align__(16) unsigned short Bsm[32][66];
  int b = blockIdx.z;
  int o0 = blockIdx.y * 64;
  int l0 = blockIdx.x * 64;
  int tid = threadIdx.x;
  int wave = tid >> 6, lane = tid & 63;
  int wm = wave >> 1, wn = wave & 1;
  int lrow = lane & 15, lg = lane >> 4;
  const unsigned short* Fp = fusedb + (size_t)b * 448 * 256;
  float4v acc[2][2];
  #pragma unroll
  for (int i = 0; i < 2; ++i)
    #pragma unroll
    for (int j = 0; j < 2; ++j) acc[i][j] = (float4v){0.f, 0.f, 0.f, 0.f};
  for (int c0 = 0; c0 < 448; c0 += 32) {
    { int r = tid >> 2, k0 = (tid & 3) * 8;
      *(short8v*)&Asm[r][k0] = *(const short8v*)(qbf + (size_t)(o0 + r) * 448 + c0 + k0); }
    { int k = tid >> 3, n0 = (tid & 7) * 8;
      short8v v = *(const short8v*)(Fp + (size_t)(c0 + k) * 256 + l0 + n0);
      *(short8v*)&Bsm[k][n0] = v; }
    __syncthreads();
    short8v af[2];
    #pragma unroll
    for (int mf = 0; mf < 2; ++mf)
      af[mf] = *(const short8v*)&Asm[wm * 32 + mf * 16 + lrow][lg * 8];
    #pragma unroll
    for (int nf = 0; nf < 2; ++nf) {
      int n = wn * 32 + nf * 16 + lrow;
      short8v bf;
      #pragma unroll
      for (int j = 0; j < 8; ++j) bf[j] = (short)Bsm[lg * 8 + j][n];
      #pragma unroll
      for (int mf = 0; mf < 2; ++mf)
        acc[mf][nf] = __builtin_amdgcn_mfma_f32_16x16x32_bf16(af[mf], bf, acc[mf][nf], 0, 0, 0);
    }
    __syncthreads();
  }
  float sv[2][4], qv[2][4];
  #pragma unroll
  for (int mf = 0; mf < 2; ++mf) {
    #pragma unroll
    for (int reg = 0; reg < 4; ++reg) {
      int r = o0 + wm * 32 + mf * 16 + lg * 4 + reg;
      float sc = scales[r], bv = bias[r];
      float s = 0.f, q = 0.f;
      #pragma unroll
      for (int nf = 0; nf < 2; ++nf) {
        int col = l0 + wn * 32 + nf * 16 + lrow;
        float val = acc[mf][nf][reg] * sc + bv;
        y[((size_t)b * 128 + r) * 256 + col] = val;
        s += val; q += val * val;
      }
      sv[mf][reg] = s; qv[mf][reg] = q;
    }
  }
  #pragma unroll
  for (int mf = 0; mf < 2; ++mf)
    #pragma unroll
    for (int reg = 0; reg < 4; ++reg)
      #pragma unroll
      for (int m = 1; m < 16; m <<= 1) {
        sv[mf][reg] += __shfl_xor(sv[mf][reg], m, 64);
        qv[mf][reg] += __shfl_xor(qv[mf][reg], m, 64);
      }
  if (lrow == 0) {
    int slot = b * 8 + blockIdx.x * 2 + wn;
    #pragma unroll
    for (int mf = 0; mf < 2; ++mf)
      #pragma unroll
      for (int reg = 0; reg < 4; ++reg) {
        int r = o0 + wm * 32 + mf * 16 + lg * 4 + reg;
        Psum[r * 512 + slot] = sv[mf][reg];
        Pssq[r * 512 + slot] = qv[mf][reg];
      }
  }
}

__global__ __launch_bounds__(256) void finalize_kernel(
    const float* __restrict__ Psum, const float* __restrict__ Pssq,
    float* __restrict__ stats) {
  int o = blockIdx.x;
  int t = threadIdx.x;
  float s = Psum[o * 512 + t] + Psum[o * 512 + 256 + t];
  float q = Pssq[o * 512 + t] + Pssq[o * 512 + 256 + t];
  __shared__ float sb[8];
  for (int m = 32; m; m >>= 1) { s += __shfl_down(s, m, 64); q += __shfl_down(q, m, 64); }
  if ((t & 63) == 0) { sb[t >> 6] = s; sb[4 + (t >> 6)] = q; }
  __syncthreads();
  if (t == 0) {
    s = sb[0] + sb[1] + sb[2] + sb[3];
    q = sb[4] + sb[5] + sb[6] + sb[7];
    float mean = s * (1.f / 16384.f);
    float var = q * (1.f / 16384.f) - mean * mean;
    stats[o] = mean;
    stats[128 + o] = rsqrtf(var + EPSV);
  }
}

__global__ __launch_bounds__(256) void final_kernel(
    const float* __restrict__ y, const float* __restrict__ stats,
    const float* __restrict__ gamma, const float* __restrict__ beta,
    float* __restrict__ out) {
  int w = threadIdx.x >> 6;
  int lane = threadIdx.x & 63;
  int bo = blockIdx.x * 4 + w;
  int o = bo & 127;
  float mean = stats[o], rs = stats[128 + o];
  float g = gamma[o], bt = beta[o];
  float4 v = *(const float4*)(y + (size_t)bo * 256 + lane * 4);
  float acc = 0.f;
  #pragma unroll
  for (int j = 0; j < 4; ++j) {
    float e = (&v.x)[j];
    float yn = (e - mean) * rs * g + bt;
    acc += yn > 0.f ? yn : expm1f(yn);
  }
  for (int m = 32; m; m >>= 1) acc += __shfl_down(acc, m, 64);
  if (lane == 0) out[bo] = acc * (1.f / 256.f);
}

extern "C" void kernel_launch(void* const* d_in, const int* in_sizes, int n_in,
                              void* d_out, int out_size, void* d_ws, size_t ws_size,
                              hipStream_t stream) {
  const float* s1     = (const float*)d_in[0];
  const float* s2     = (const float*)d_in[1];
  const float* s3     = (const float*)d_in[2];
  const float* alpha  = (const float*)d_in[3];
  const float* weight = (const float*)d_in[4];
  const float* bias   = (const float*)d_in[5];
  const float* gamma  = (const float*)d_in[6];
  const float* beta   = (const float*)d_in[7];
  float* out = (float*)d_out;

  char* ws = (char*)d_ws;
  unsigned short* fusedb = (unsigned short*)ws;              // 14,680,064
  unsigned short* qbf    = (unsigned short*)(ws + 14680064); //    114,688
  float* scales          = (float*)(ws + 14794752);          //        512
  float* Psum            = (float*)(ws + 14795264);          //     32,768
  float* Pssq            = (float*)(ws + 14828032);          //     32,768
  // fallback extras
  float* y               = (float*)(ws + 14860800);          //  8,388,608
  float* stats           = (float*)(ws + 23249408);          //      1,024
  float* PsumL           = (float*)(ws + 23250432);          //    262,144
  float* PssqL           = (float*)(ws + 23512576);          //    262,144

  pool_quant_kernel<<<28800, 256, 0, stream>>>(s1, s2, s3, alpha, weight,
                                               fusedb, qbf, scales);

  int coop = 0;
  hipDeviceGetAttribute(&coop, hipDeviceAttributeCooperativeLaunch, 0);

  bool done = false;
  if (coop) {
    void* args[] = {(void*)&qbf, (void*)&scales, (void*)&fusedb, (void*)&bias,
                    (void*)&gamma, (void*)&beta, (void*)&Psum, (void*)&Pssq,
                    (void*)&out};
    hipError_t err = hipLaunchCooperativeKernel(
        (const void*)fused_tail_kernel, dim3(64, 2, 1), dim3(256, 1, 1),
        args, 0, stream);
    done = (err == hipSuccess);
  }
  if (!done) {
    dim3 g(4, 2, 64);
    mfma_gemm_kernel<<<g, 256, 0, stream>>>(qbf, scales, fusedb, bias, y, PsumL, PssqL);
    finalize_kernel<<<128, 256, 0, stream>>>(PsumL, PssqL, stats);
    final_kernel<<<2048, 256, 0, stream>>>(y, stats, gamma, beta, out);
  }
}

// Round 7
// 102.783 us; speedup vs baseline: 1.4477x; 1.4477x over previous
//
#include <hip/hip_runtime.h>
#include <hip/hip_bf16.h>

#define EPSV 1e-5f

typedef __attribute__((ext_vector_type(8))) short short8v;
typedef __attribute__((ext_vector_type(4))) float float4v;

__device__ inline unsigned short f2bf(float x) {
  __hip_bfloat16 h = __float2bfloat16(x);   // RNE
  return *reinterpret_cast<unsigned short*>(&h);
}
__device__ inline float bf2f(unsigned short b) {
  unsigned u = ((unsigned)b) << 16;
  float f;
  __builtin_memcpy(&f, &u, 4);
  return f;
}

// ------------- Kernel 1: pool (+softmax scale) with quant tail blocks -------
// Blocks [0, 28672): one (b, global-channel) row of adaptive avg-pool -> bf16.
// Blocks [28672, 28800): 2-bit weight quant row -> exact bf16 q + f32 scale.
__global__ __launch_bounds__(256) void pool_quant_kernel(
    const float* __restrict__ s1, const float* __restrict__ s2,
    const float* __restrict__ s3, const float* __restrict__ alpha,
    const float* __restrict__ w, unsigned short* __restrict__ fusedb,
    unsigned short* __restrict__ qbf, float* __restrict__ scales) {
  __shared__ float row[5000];
  int bid = blockIdx.x;
  int t = threadIdx.x;

  if (bid >= 28672) {               // ---- quant tail ----
    int o = bid - 28672;            // 0..127
    const float* wr = w + o * 448;
    float m = 0.f;
    for (int c = t; c < 448; c += 256) m = fmaxf(m, fabsf(wr[c]));
    float* sm = row;                // reuse LDS
    for (int off = 32; off; off >>= 1) m = fmaxf(m, __shfl_down(m, off, 64));
    if ((t & 63) == 0) sm[t >> 6] = m;
    __syncthreads();
    m = fmaxf(fmaxf(sm[0], sm[1]), fmaxf(sm[2], sm[3]));
    float scale = fmaxf(m, 1e-8f);  // qp = 1 for 2-bit symmetric
    for (int c = t; c < 448; c += 256) {
      float q = rintf(wr[c] / scale);      // RNE == jnp.round
      q = fminf(fmaxf(q, -2.f), 1.f);
      qbf[o * 448 + c] = f2bf(q);          // q in {-2,-1,0,1}: exact bf16
    }
    if (t == 0) scales[o] = scale;
    return;
  }

  // ---- pool path ----
  int b = bid / 448;
  int cg_ = bid % 448;
  const float* src; int C, L, c, widx;
  if (cg_ < 256)      { src = s1; C = 256; L = 5000; c = cg_;       widx = 0; }
  else if (cg_ < 384) { src = s2; C = 128; L = 2500; c = cg_ - 256; widx = 1; }
  else                { src = s3; C = 64;  L = 625;  c = cg_ - 384; widx = 2; }

  float a0 = alpha[0], a1 = alpha[1], a2 = alpha[2];
  float mx = fmaxf(a0, fmaxf(a1, a2));
  float e0 = expf(a0 - mx), e1 = expf(a1 - mx), e2 = expf(a2 - mx);
  float wst = ((widx == 0) ? e0 : (widx == 1) ? e1 : e2) / (e0 + e1 + e2);

  const float* rowp = src + ((size_t)b * C + c) * L;
  if ((L & 3) == 0) {
    const float4* rp4 = (const float4*)rowp;
    int L4 = L >> 2;
    for (int i = t; i < L4; i += 256) {
      float4 v = rp4[i];
      int j = i << 2;
      row[j] = v.x; row[j + 1] = v.y; row[j + 2] = v.z; row[j + 3] = v.w;
    }
  } else {
    for (int i = t; i < L; i += 256) row[i] = rowp[i];
  }
  __syncthreads();

  int l = t;
  int start = (l * L) >> 8;
  int end = ((l + 1) * L + 255) >> 8;
  float s = 0.f;
  for (int i = start; i < end; ++i) s += row[i];
  float v = s / (float)(end - start) * wst;
  fusedb[((size_t)b * 448 + cg_) * 256 + l] = f2bf(v);
}

// ------------- Kernel 2: MFMA GEMM -> bf16 y + BN partials ------------------
// Block: 256 thr (4 waves as 2x2), 64x64 output tile, K-step 32.
__global__ __launch_bounds__(256) void mfma_gemm_kernel(
    const unsigned short* __restrict__ qbf, const float* __restrict__ scales,
    const unsigned short* __restrict__ fusedb, const float* __restrict__ bias,
    unsigned short* __restrict__ ybf, float* __restrict__ Psum,
    float* __restrict__ Pssq) {
  __shared__ __align__(16) unsigned short Asm[64][40];
  __shared__ __align__(16) unsigned short Bsm[32][66];
  int b = blockIdx.z;
  int o0 = blockIdx.y * 64;
  int l0 = blockIdx.x * 64;
  int tid = threadIdx.x;
  int wave = tid >> 6, lane = tid & 63;
  int wm = wave >> 1, wn = wave & 1;
  int lrow = lane & 15, lg = lane >> 4;
  const unsigned short* Fp = fusedb + (size_t)b * 448 * 256;
  float4v acc[2][2];
  #pragma unroll
  for (int i = 0; i < 2; ++i)
    #pragma unroll
    for (int j = 0; j < 2; ++j) acc[i][j] = (float4v){0.f, 0.f, 0.f, 0.f};
  for (int c0 = 0; c0 < 448; c0 += 32) {
    { int r = tid >> 2, k0 = (tid & 3) * 8;
      *(short8v*)&Asm[r][k0] = *(const short8v*)(qbf + (size_t)(o0 + r) * 448 + c0 + k0); }
    { int k = tid >> 3, n0 = (tid & 7) * 8;
      short8v v = *(const short8v*)(Fp + (size_t)(c0 + k) * 256 + l0 + n0);
      *(short8v*)&Bsm[k][n0] = v; }
    __syncthreads();
    short8v af[2];
    #pragma unroll
    for (int mf = 0; mf < 2; ++mf)
      af[mf] = *(const short8v*)&Asm[wm * 32 + mf * 16 + lrow][lg * 8];
    #pragma unroll
    for (int nf = 0; nf < 2; ++nf) {
      int n = wn * 32 + nf * 16 + lrow;
      short8v bf;
      #pragma unroll
      for (int j = 0; j < 8; ++j) bf[j] = (short)Bsm[lg * 8 + j][n];
      #pragma unroll
      for (int mf = 0; mf < 2; ++mf)
        acc[mf][nf] = __builtin_amdgcn_mfma_f32_16x16x32_bf16(af[mf], bf, acc[mf][nf], 0, 0, 0);
    }
    __syncthreads();
  }
  float sv[2][4], qv[2][4];
  #pragma unroll
  for (int mf = 0; mf < 2; ++mf) {
    #pragma unroll
    for (int reg = 0; reg < 4; ++reg) {
      int r = o0 + wm * 32 + mf * 16 + lg * 4 + reg;
      float sc = scales[r], bv = bias[r];
      float s = 0.f, q = 0.f;
      #pragma unroll
      for (int nf = 0; nf < 2; ++nf) {
        int col = l0 + wn * 32 + nf * 16 + lrow;
        float val = acc[mf][nf][reg] * sc + bv;
        ybf[((size_t)b * 128 + r) * 256 + col] = f2bf(val);
        s += val; q += val * val;              // partials from f32 (pre-round)
      }
      sv[mf][reg] = s; qv[mf][reg] = q;
    }
  }
  #pragma unroll
  for (int mf = 0; mf < 2; ++mf)
    #pragma unroll
    for (int reg = 0; reg < 4; ++reg)
      #pragma unroll
      for (int m = 1; m < 16; m <<= 1) {
        sv[mf][reg] += __shfl_xor(sv[mf][reg], m, 64);
        qv[mf][reg] += __shfl_xor(qv[mf][reg], m, 64);
      }
  if (lrow == 0) {
    int slot = b * 8 + blockIdx.x * 2 + wn;   // 0..511 fixed slot
    #pragma unroll
    for (int mf = 0; mf < 2; ++mf)
      #pragma unroll
      for (int reg = 0; reg < 4; ++reg) {
        int r = o0 + wm * 32 + mf * 16 + lg * 4 + reg;
        Psum[r * 512 + slot] = sv[mf][reg];
        Pssq[r * 512 + slot] = qv[mf][reg];
      }
  }
}

// ------------- Kernel 3: inline stats + BN + ELU + mean over L --------------
// 2048 blocks x 4 waves; each wave owns one (b, o) row; stats recomputed
// per-wave from the 512 L2-hot partials (16 loads + shuffles, ~free).
__global__ __launch_bounds__(256) void final_kernel(
    const unsigned short* __restrict__ ybf, const float* __restrict__ Psum,
    const float* __restrict__ Pssq, const float* __restrict__ gamma,
    const float* __restrict__ beta, float* __restrict__ out) {
  int w = threadIdx.x >> 6;
  int lane = threadIdx.x & 63;
  int bo = blockIdx.x * 4 + w;     // b*128 + o
  int o = bo & 127;

  // per-wave stats reduction over 512 partials
  float s = 0.f, q = 0.f;
  const float* Pp = Psum + o * 512 + lane * 8;
  const float* Qp = Pssq + o * 512 + lane * 8;
  #pragma unroll
  for (int i = 0; i < 8; ++i) { s += Pp[i]; q += Qp[i]; }
  #pragma unroll
  for (int m = 1; m < 64; m <<= 1) {
    s += __shfl_xor(s, m, 64);
    q += __shfl_xor(q, m, 64);
  }
  float mean = s * (1.f / 16384.f);
  float var = q * (1.f / 16384.f) - mean * mean;
  float rs = rsqrtf(var + EPSV);
  float a = rs * gamma[o];
  float bb = beta[o] - mean * a;

  ushort4 v = *(const ushort4*)(ybf + (size_t)bo * 256 + lane * 4);
  float acc = 0.f;
  #pragma unroll
  for (int j = 0; j < 4; ++j) {
    float e = bf2f((&v.x)[j]);
    float yn = e * a + bb;
    acc += yn > 0.f ? yn : expm1f(yn);
  }
  for (int m = 32; m; m >>= 1) acc += __shfl_down(acc, m, 64);
  if (lane == 0) out[bo] = acc * (1.f / 256.f);
}

extern "C" void kernel_launch(void* const* d_in, const int* in_sizes, int n_in,
                              void* d_out, int out_size, void* d_ws, size_t ws_size,
                              hipStream_t stream) {
  const float* s1     = (const float*)d_in[0];
  const float* s2     = (const float*)d_in[1];
  const float* s3     = (const float*)d_in[2];
  const float* alpha  = (const float*)d_in[3];
  const float* weight = (const float*)d_in[4];
  const float* bias   = (const float*)d_in[5];
  const float* gamma  = (const float*)d_in[6];
  const float* beta   = (const float*)d_in[7];
  float* out = (float*)d_out;

  char* ws = (char*)d_ws;
  unsigned short* fusedb = (unsigned short*)ws;              // 14,680,064
  unsigned short* qbf    = (unsigned short*)(ws + 14680064); //    114,688
  float* scales          = (float*)(ws + 14794752);          //        512
  unsigned short* ybf    = (unsigned short*)(ws + 14795264); //  4,194,304
  float* Psum            = (float*)(ws + 18989568);          //    262,144
  float* Pssq            = (float*)(ws + 19251712);          //    262,144

  pool_quant_kernel<<<28800, 256, 0, stream>>>(s1, s2, s3, alpha, weight,
                                               fusedb, qbf, scales);
  dim3 g(4, 2, 64);
  mfma_gemm_kernel<<<g, 256, 0, stream>>>(qbf, scales, fusedb, bias, ybf,
                                          Psum, Pssq);
  final_kernel<<<2048, 256, 0, stream>>>(ybf, Psum, Pssq, gamma, beta, out);
}

// Round 9
// 100.689 us; speedup vs baseline: 1.4778x; 1.0208x over previous
//
#include <hip/hip_runtime.h>
#include <hip/hip_bf16.h>

#define EPSV 1e-5f

typedef __attribute__((ext_vector_type(8))) short short8v;
typedef __attribute__((ext_vector_type(4))) float float4v;

__device__ inline unsigned short f2bf(float x) {
  __hip_bfloat16 h = __float2bfloat16(x);   // RNE
  return *reinterpret_cast<unsigned short*>(&h);
}
__device__ inline float bf2f(unsigned short b) {
  unsigned u = ((unsigned)b) << 16;
  float f;
  __builtin_memcpy(&f, &u, 4);
  return f;
}

// ---- pool row body, float4-aligned rows (L%4==0, base 16B-aligned) ---------
template <int L, int MAXW>
__device__ __forceinline__ void pool_row_vec(
    const float* __restrict__ rowp, float wst,
    unsigned short* __restrict__ outp, float* __restrict__ row, int t) {
  constexpr int L4 = L / 4;
  constexpr int ITER = (L4 + 255) / 256;
  const float4v* rp4 = (const float4v*)rowp;   // clang ext-vector: nt-load OK
  #pragma unroll
  for (int i = 0; i < ITER; ++i) {
    int idx = t + 256 * i;
    if (ITER * 256 == L4 || idx < L4) {
      float4v v = __builtin_nontemporal_load(rp4 + idx);
      *(float4v*)&row[idx * 4] = v;
    }
  }
  if (t < MAXW) row[L + t] = 0.f;       // zero pad so masked reads are safe
  __syncthreads();
  int start = (t * L) >> 8;             // floor(t*L/256)
  int end = ((t + 1) * L + 255) >> 8;   // ceil((t+1)*L/256)
  int width = end - start;
  float s = 0.f;
  #pragma unroll
  for (int i = 0; i < MAXW; ++i) {      // independent masked LDS reads
    float v = row[start + i];
    s += (i < width) ? v : 0.f;
  }
  outp[t] = f2bf(s / (float)width * wst);
}

// ---- pool row body, scalar loads (stage3: L=625, rows only 4B-aligned) -----
template <int L, int MAXW>
__device__ __forceinline__ void pool_row_scalar(
    const float* __restrict__ rowp, float wst,
    unsigned short* __restrict__ outp, float* __restrict__ row, int t) {
  constexpr int ITER = (L + 255) / 256;
  #pragma unroll
  for (int i = 0; i < ITER; ++i) {
    int idx = t + 256 * i;
    if (idx < L) row[idx] = __builtin_nontemporal_load(rowp + idx);
  }
  if (t < MAXW) row[L + t] = 0.f;
  __syncthreads();
  int start = (t * L) >> 8;
  int end = ((t + 1) * L + 255) >> 8;
  int width = end - start;
  float s = 0.f;
  #pragma unroll
  for (int i = 0; i < MAXW; ++i) {
    float v = row[start + i];
    s += (i < width) ? v : 0.f;
  }
  outp[t] = f2bf(s / (float)width * wst);
}

// ------------- Kernel 1: pool (+softmax scale) with quant tail blocks -------
// Stage-major block order (heavy stage1 first -> no straggler tail):
//   [0,16384): stage1   [16384,24576): stage2   [24576,28672): stage3
//   [28672,28800): 2-bit weight quant rows
__global__ __launch_bounds__(256) void pool_quant_kernel(
    const float* __restrict__ s1, const float* __restrict__ s2,
    const float* __restrict__ s3, const float* __restrict__ alpha,
    const float* __restrict__ w, unsigned short* __restrict__ fusedb,
    unsigned short* __restrict__ qbf, float* __restrict__ scales) {
  __shared__ float row[5024];
  int bid = blockIdx.x;
  int t = threadIdx.x;

  if (bid >= 28672) {               // ---- quant tail ----
    int o = bid - 28672;            // 0..127
    const float* wr = w + o * 448;
    float m = 0.f;
    for (int c = t; c < 448; c += 256) m = fmaxf(m, fabsf(wr[c]));
    float* sm = row;                // reuse LDS
    for (int off = 32; off; off >>= 1) m = fmaxf(m, __shfl_down(m, off, 64));
    if ((t & 63) == 0) sm[t >> 6] = m;
    __syncthreads();
    m = fmaxf(fmaxf(sm[0], sm[1]), fmaxf(sm[2], sm[3]));
    float scale = fmaxf(m, 1e-8f);  // qp = 1 for 2-bit symmetric
    for (int c = t; c < 448; c += 256) {
      float q = rintf(wr[c] / scale);      // RNE == jnp.round
      q = fminf(fmaxf(q, -2.f), 1.f);
      qbf[o * 448 + c] = f2bf(q);          // q in {-2,-1,0,1}: exact bf16
    }
    if (t == 0) scales[o] = scale;
    return;
  }

  float a0 = alpha[0], a1 = alpha[1], a2 = alpha[2];
  float mx = fmaxf(a0, fmaxf(a1, a2));
  float e0 = expf(a0 - mx), e1 = expf(a1 - mx), e2 = expf(a2 - mx);
  float esum = e0 + e1 + e2;

  if (bid < 16384) {                // ---- stage1: L=5000 ----
    int b = bid >> 8, c = bid & 255;
    const float* rowp = s1 + ((size_t)b * 256 + c) * 5000;
    unsigned short* outp = fusedb + ((size_t)b * 448 + c) * 256;
    pool_row_vec<5000, 21>(rowp, e0 / esum, outp, row, t);
  } else if (bid < 24576) {         // ---- stage2: L=2500 ----
    int q = bid - 16384;
    int b = q >> 7, c = q & 127;
    const float* rowp = s2 + ((size_t)b * 128 + c) * 2500;
    unsigned short* outp = fusedb + ((size_t)b * 448 + 256 + c) * 256;
    pool_row_vec<2500, 11>(rowp, e1 / esum, outp, row, t);
  } else {                          // ---- stage3: L=625 ----
    int q = bid - 24576;
    int b = q >> 6, c = q & 63;
    const float* rowp = s3 + ((size_t)b * 64 + c) * 625;
    unsigned short* outp = fusedb + ((size_t)b * 448 + 384 + c) * 256;
    pool_row_scalar<625, 4>(rowp, e2 / esum, outp, row, t);
  }
}

// ------------- Kernel 2: MFMA GEMM -> bf16 y + BN partials ------------------
// Block: 256 thr (4 waves as 2x2), 64x64 output tile, K-step 32.
__global__ __launch_bounds__(256) void mfma_gemm_kernel(
    const unsigned short* __restrict__ qbf, const float* __restrict__ scales,
    const unsigned short* __restrict__ fusedb, const float* __restrict__ bias,
    unsigned short* __restrict__ ybf, float* __restrict__ Psum,
    float* __restrict__ Pssq) {
  __shared__ __align__(16) unsigned short Asm[64][40];
  __shared__ __align__(16) unsigned short Bsm[32][66];
  int b = blockIdx.z;
  int o0 = blockIdx.y * 64;
  int l0 = blockIdx.x * 64;
  int tid = threadIdx.x;
  int wave = tid >> 6, lane = tid & 63;
  int wm = wave >> 1, wn = wave & 1;
  int lrow = lane & 15, lg = lane >> 4;
  const unsigned short* Fp = fusedb + (size_t)b * 448 * 256;
  float4v acc[2][2];
  #pragma unroll
  for (int i = 0; i < 2; ++i)
    #pragma unroll
    for (int j = 0; j < 2; ++j) acc[i][j] = (float4v){0.f, 0.f, 0.f, 0.f};
  for (int c0 = 0; c0 < 448; c0 += 32) {
    { int r = tid >> 2, k0 = (tid & 3) * 8;
      *(short8v*)&Asm[r][k0] = *(const short8v*)(qbf + (size_t)(o0 + r) * 448 + c0 + k0); }
    { int k = tid >> 3, n0 = (tid & 7) * 8;
      short8v v = *(const short8v*)(Fp + (size_t)(c0 + k) * 256 + l0 + n0);
      *(short8v*)&Bsm[k][n0] = v; }
    __syncthreads();
    short8v af[2];
    #pragma unroll
    for (int mf = 0; mf < 2; ++mf)
      af[mf] = *(const short8v*)&Asm[wm * 32 + mf * 16 + lrow][lg * 8];
    #pragma unroll
    for (int nf = 0; nf < 2; ++nf) {
      int n = wn * 32 + nf * 16 + lrow;
      short8v bf;
      #pragma unroll
      for (int j = 0; j < 8; ++j) bf[j] = (short)Bsm[lg * 8 + j][n];
      #pragma unroll
      for (int mf = 0; mf < 2; ++mf)
        acc[mf][nf] = __builtin_amdgcn_mfma_f32_16x16x32_bf16(af[mf], bf, acc[mf][nf], 0, 0, 0);
    }
    __syncthreads();
  }
  float sv[2][4], qv[2][4];
  #pragma unroll
  for (int mf = 0; mf < 2; ++mf) {
    #pragma unroll
    for (int reg = 0; reg < 4; ++reg) {
      int r = o0 + wm * 32 + mf * 16 + lg * 4 + reg;
      float sc = scales[r], bv = bias[r];
      float s = 0.f, q = 0.f;
      #pragma unroll
      for (int nf = 0; nf < 2; ++nf) {
        int col = l0 + wn * 32 + nf * 16 + lrow;
        float val = acc[mf][nf][reg] * sc + bv;
        ybf[((size_t)b * 128 + r) * 256 + col] = f2bf(val);
        s += val; q += val * val;              // partials from f32 (pre-round)
      }
      sv[mf][reg] = s; qv[mf][reg] = q;
    }
  }
  #pragma unroll
  for (int mf = 0; mf < 2; ++mf)
    #pragma unroll
    for (int reg = 0; reg < 4; ++reg)
      #pragma unroll
      for (int m = 1; m < 16; m <<= 1) {
        sv[mf][reg] += __shfl_xor(sv[mf][reg], m, 64);
        qv[mf][reg] += __shfl_xor(qv[mf][reg], m, 64);
      }
  if (lrow == 0) {
    int slot = b * 8 + blockIdx.x * 2 + wn;   // 0..511 fixed slot
    #pragma unroll
    for (int mf = 0; mf < 2; ++mf)
      #pragma unroll
      for (int reg = 0; reg < 4; ++reg) {
        int r = o0 + wm * 32 + mf * 16 + lg * 4 + reg;
        Psum[r * 512 + slot] = sv[mf][reg];
        Pssq[r * 512 + slot] = qv[mf][reg];
      }
  }
}

// ------------- Kernel 3: inline stats + BN + ELU + mean over L --------------
// 2048 blocks x 4 waves; each wave owns one (b, o) row; stats recomputed
// per-wave from the 512 L2-hot partials (16 loads + shuffles, ~free).
__global__ __launch_bounds__(256) void final_kernel(
    const unsigned short* __restrict__ ybf, const float* __restrict__ Psum,
    const float* __restrict__ Pssq, const float* __restrict__ gamma,
    const float* __restrict__ beta, float* __restrict__ out) {
  int w = threadIdx.x >> 6;
  int lane = threadIdx.x & 63;
  int bo = blockIdx.x * 4 + w;     // b*128 + o
  int o = bo & 127;

  // per-wave stats reduction over 512 partials
  float s = 0.f, q = 0.f;
  const float* Pp = Psum + o * 512 + lane * 8;
  const float* Qp = Pssq + o * 512 + lane * 8;
  #pragma unroll
  for (int i = 0; i < 8; ++i) { s += Pp[i]; q += Qp[i]; }
  #pragma unroll
  for (int m = 1; m < 64; m <<= 1) {
    s += __shfl_xor(s, m, 64);
    q += __shfl_xor(q, m, 64);
  }
  float mean = s * (1.f / 16384.f);
  float var = q * (1.f / 16384.f) - mean * mean;
  float rs = rsqrtf(var + EPSV);
  float a = rs * gamma[o];
  float bb = beta[o] - mean * a;

  ushort4 v = *(const ushort4*)(ybf + (size_t)bo * 256 + lane * 4);
  float acc = 0.f;
  #pragma unroll
  for (int j = 0; j < 4; ++j) {
    float e = bf2f((&v.x)[j]);
    float yn = e * a + bb;
    acc += yn > 0.f ? yn : expm1f(yn);
  }
  for (int m = 32; m; m >>= 1) acc += __shfl_down(acc, m, 64);
  if (lane == 0) out[bo] = acc * (1.f / 256.f);
}

extern "C" void kernel_launch(void* const* d_in, const int* in_sizes, int n_in,
                              void* d_out, int out_size, void* d_ws, size_t ws_size,
                              hipStream_t stream) {
  const float* s1     = (const float*)d_in[0];
  const float* s2     = (const float*)d_in[1];
  const float* s3     = (const float*)d_in[2];
  const float* alpha  = (const float*)d_in[3];
  const float* weight = (const float*)d_in[4];
  const float* bias   = (const float*)d_in[5];
  const float* gamma  = (const float*)d_in[6];
  const float* beta   = (const float*)d_in[7];
  float* out = (float*)d_out;

  char* ws = (char*)d_ws;
  unsigned short* fusedb = (unsigned short*)ws;              // 14,680,064
  unsigned short* qbf    = (unsigned short*)(ws + 14680064); //    114,688
  float* scales          = (float*)(ws + 14794752);          //        512
  unsigned short* ybf    = (unsigned short*)(ws + 14795264); //  4,194,304
  float* Psum            = (float*)(ws + 18989568);          //    262,144
  float* Pssq            = (float*)(ws + 19251712);          //    262,144

  pool_quant_kernel<<<28800, 256, 0, stream>>>(s1, s2, s3, alpha, weight,
                                               fusedb, qbf, scales);
  dim3 g(4, 2, 64);
  mfma_gemm_kernel<<<g, 256, 0, stream>>>(qbf, scales, fusedb, bias, ybf,
                                          Psum, Pssq);
  final_kernel<<<2048, 256, 0, stream>>>(ybf, Psum, Pssq, gamma, beta, out);
}